// Round 4
// baseline (405.478 us; speedup 1.0000x reference)
//
#include <hip/hip_runtime.h>
#include <math.h>

#define NP 16384      // pixels per map (128*128)
#define CH 256        // channels (K)
#define WDIM 128
#define EPSF 1e-8f

#define TOPK 4
#define CHUNK 32              // cols per LDS chunk
#define SPLITS 4
#define COLS_PER_SPLIT (NP / SPLITS)       // 4096
#define NCHUNK (COLS_PER_SPLIT / CHUNK)    // 128
#define ROWS 128              // rows per block (4 waves x 32)
#define CHUNK_BYTES (CHUNK * CH * 2)       // 16384

typedef short short8 __attribute__((ext_vector_type(8)));
typedef float floatx4 __attribute__((ext_vector_type(4)));

typedef __attribute__((address_space(1))) const unsigned int gu32;
typedef __attribute__((address_space(3))) unsigned int lu32;

#define NEG_INF_F __int_as_float(0xFF800000)

// ------------------------------------------------------------------
// prep: per-pixel 1/||d||, write fp32 normalized transposed [pix][256]
// and bf16 normalized swizzled (element ch stored at ch ^ ((pix&7)<<3))
// ------------------------------------------------------------------
__global__ __launch_bounds__(256) void prep_kernel(
    const float* __restrict__ A, const float* __restrict__ B,
    float* __restrict__ AT, float* __restrict__ BT,
    unsigned short* __restrict__ Abf, unsigned short* __restrict__ Bbf)
{
    __shared__ float tile[64 * 257];
    __shared__ float rnv[64];
    const int bid = blockIdx.x;
    const float* __restrict__ src = (bid < 256) ? A : B;
    float* __restrict__ dstT = (bid < 256) ? AT : BT;
    unsigned short* __restrict__ dstb = (bid < 256) ? Abf : Bbf;
    const int pixBase = (bid & 255) * 64;
    const int t = threadIdx.x;

    for (int k = 0; k < 64 * 256; k += 256) {
        int idx = k + t;
        int p = idx & 63;
        int c = idx >> 6;
        tile[p * 257 + c] = src[(size_t)c * NP + pixBase + p];
    }
    __syncthreads();
    if (t < 64) {
        float s = 0.f;
        for (int c = 0; c < 256; ++c) { float v = tile[t * 257 + c]; s = fmaf(v, v, s); }
        rnv[t] = 1.0f / sqrtf(s);
    }
    __syncthreads();
    // fp32 transposed normalized
    for (int k = 0; k < 64 * 256; k += 256) {
        int idx = k + t;
        int p = idx >> 8;
        int c = idx & 255;
        dstT[((size_t)(pixBase + p) << 8) + c] = tile[p * 257 + c] * rnv[p];
    }
    // bf16 swizzled normalized (write pairs)
    for (int k = 0; k < 64 * 128; k += 256) {
        int idx = k + t;
        int p = idx >> 7;
        int c2 = (idx & 127) * 2;
        float rn = rnv[p];
        float v0 = tile[p * 257 + c2] * rn;
        float v1 = tile[p * 257 + c2 + 1] * rn;
        unsigned u0 = __float_as_uint(v0); u0 = (u0 + 0x7fffu + ((u0 >> 16) & 1u)) >> 16;
        unsigned u1 = __float_as_uint(v1); u1 = (u1 + 0x7fffu + ((u1 >> 16) & 1u)) >> 16;
        unsigned sw = ((unsigned)(p & 7)) << 3;
        int e = ((pixBase + p) << 8) + (c2 ^ (int)sw);
        *(unsigned*)(dstb + e) = (u0 & 0xffffu) | (u1 << 16);
    }
}

// ------------------------------------------------------------------
// simk: bf16 MFMA sim sweep, packed-key branchless per-lane top-4.
// grid 1024: pass(2) x rowTile(128) x split(4). Block: 4 waves x 32 rows.
// Swapped operands: cols = M (A-operand, LDS), rows = N (B-operand, REGS).
// B-operand fragments are pinned in VGPRs via asm so they are loaded
// from L2 exactly once per block (round-3 was L2-BW-bound on re-reads).
// key = (sim_bits & 0xFFFFF000) | col_local(12b); float-orderable.
// ------------------------------------------------------------------
__global__ __launch_bounds__(256, 3) void simk_kernel(
    const unsigned short* __restrict__ Abf, const unsigned short* __restrict__ Bbf,
    int* __restrict__ cand)
{
    __shared__ __align__(16) char smem[2 * CHUNK_BYTES];  // 32 KB
    const int bid = blockIdx.x;
    const int pass = bid >> 9;            // 0..1
    const int rt = (bid >> 2) & 127;      // 0..127
    const int split = bid & 3;
    const unsigned short* __restrict__ rows_b = pass ? Bbf : Abf;
    const unsigned short* __restrict__ cols_b = pass ? Abf : Bbf;
    const int t = threadIdx.x;
    const int w = t >> 6;
    const int l = t & 63;
    const int l15 = l & 15, lhi = l >> 4;
    const int rowBase = rt * ROWS;
    const int colBase = split * COLS_PER_SPLIT;

    // --- preload row-descriptor fragments (B-operand): 2 ni x 8 kk ---
    short8 Bfr[2][8];
#pragma unroll
    for (int ni = 0; ni < 2; ++ni) {
        int pix = rowBase + w * 32 + ni * 16 + l15;
        const unsigned short* pr = rows_b + ((size_t)pix << 8);
        int sw = (pix & 7) << 3;
#pragma unroll
        for (int kk = 0; kk < 8; ++kk) {
            int ke = kk * 32 + lhi * 8;
            Bfr[ni][kk] = *(const short8*)(pr + (ke ^ sw));
        }
    }
    // Pin each fragment in VGPRs: the asm result is opaque, so the
    // compiler cannot rematerialize the load per chunk (round-3 bug).
#pragma unroll
    for (int ni = 0; ni < 2; ++ni)
#pragma unroll
        for (int kk = 0; kk < 8; ++kk)
            asm volatile("" : "+v"(Bfr[ni][kk]));

    // --- precompute LDS byte offsets for A frags (mi=0; mi=1 is +8192) ---
    int aoff[8];
    {
        int cp = l15;
        int sw = (cp & 7) << 3;
#pragma unroll
        for (int kk = 0; kk < 8; ++kk) {
            int ke = kk * 32 + lhi * 8;
            aoff[kk] = (cp * 256 + (ke ^ sw)) * 2;
        }
    }

    // packed-key top-4, sorted descending
    float tv[2][TOPK];
#pragma unroll
    for (int ni = 0; ni < 2; ++ni)
#pragma unroll
        for (int s = 0; s < TOPK; ++s) tv[ni][s] = NEG_INF_F;

    const char* gbase = (const char*)(cols_b + ((size_t)colBase << 8));
    const floatx4 fzero = {0.f, 0.f, 0.f, 0.f};

    // stage chunk 0
#pragma unroll
    for (int r = 0; r < 4; ++r) {
        int off = w * 4096 + r * 1024;
        __builtin_amdgcn_global_load_lds((gu32*)(gbase + off + l * 16),
                                         (lu32*)(smem + off), 16, 0, 0);
    }
    __syncthreads();

    for (int c = 0; c < NCHUNK; ++c) {
        // stage next chunk (drained by the end-of-chunk barrier)
        int nc = (c + 1 < NCHUNK) ? (c + 1) : c;
        const char* gn = gbase + (size_t)nc * CHUNK_BYTES;
        char* bufn = smem + ((c + 1) & 1) * CHUNK_BYTES;
#pragma unroll
        for (int r = 0; r < 4; ++r) {
            int off = w * 4096 + r * 1024;
            __builtin_amdgcn_global_load_lds((gu32*)(gn + off + l * 16),
                                             (lu32*)(bufn + off), 16, 0, 0);
        }

        const char* buf = smem + (c & 1) * CHUNK_BYTES;
        floatx4 acc[2][2];
        // kk = 0 peeled: accumulate from hoisted zero (no acc init movs)
        {
            short8 a0 = *(const short8*)(buf + aoff[0]);
            short8 a1 = *(const short8*)(buf + aoff[0] + 8192);
#pragma unroll
            for (int ni = 0; ni < 2; ++ni) {
                acc[0][ni] = __builtin_amdgcn_mfma_f32_16x16x32_bf16(a0, Bfr[ni][0], fzero, 0, 0, 0);
                acc[1][ni] = __builtin_amdgcn_mfma_f32_16x16x32_bf16(a1, Bfr[ni][0], fzero, 0, 0, 0);
            }
        }
#pragma unroll
        for (int kk = 1; kk < 8; ++kk) {
            short8 a0 = *(const short8*)(buf + aoff[kk]);
            short8 a1 = *(const short8*)(buf + aoff[kk] + 8192);
#pragma unroll
            for (int ni = 0; ni < 2; ++ni) {
                acc[0][ni] = __builtin_amdgcn_mfma_f32_16x16x32_bf16(a0, Bfr[ni][kk], acc[0][ni], 0, 0, 0);
                acc[1][ni] = __builtin_amdgcn_mfma_f32_16x16x32_bf16(a1, Bfr[ni][kk], acc[1][ni], 0, 0, 0);
            }
        }

        // packed-key branchless top-4: 8 VALU per value
        const int cS = c << 5;
#pragma unroll
        for (int mi = 0; mi < 2; ++mi) {
#pragma unroll
            for (int reg = 0; reg < 4; ++reg) {
                const int ib = (lhi * 4 + mi * 16 + reg) | cS;
#pragma unroll
                for (int ni = 0; ni < 2; ++ni) {
                    int kbits = (__float_as_int(acc[mi][ni][reg]) & 0xFFFFF000) | ib;
                    float fk = __int_as_float(kbits);
                    float h;
                    h = fmaxf(tv[ni][0], fk); fk = fminf(tv[ni][0], fk); tv[ni][0] = h;
                    h = fmaxf(tv[ni][1], fk); fk = fminf(tv[ni][1], fk); tv[ni][1] = h;
                    h = fmaxf(tv[ni][2], fk); fk = fminf(tv[ni][2], fk); tv[ni][2] = h;
                    tv[ni][3] = fmaxf(tv[ni][3], fk);
                }
            }
        }
        __syncthreads();
    }

    // --- merge per row: 4 lanes x top4 packed keys -> top-6 per split ---
    int4* mrg = (int4*)smem;   // [128 rows][4 lhi] int4 = 8 KB
#pragma unroll
    for (int ni = 0; ni < 2; ++ni) {
        int rloc = w * 32 + ni * 16 + l15;
        int4 p;
        p.x = __float_as_int(tv[ni][0]);
        p.y = __float_as_int(tv[ni][1]);
        p.z = __float_as_int(tv[ni][2]);
        p.w = __float_as_int(tv[ni][3]);
        mrg[rloc * 4 + lhi] = p;
    }
    __syncthreads();
    if (t < ROWS) {
        float bv[6];
#pragma unroll
        for (int s = 0; s < 6; ++s) bv[s] = NEG_INF_F;
        for (int q = 0; q < 4; ++q) {
            int4 p = mrg[t * 4 + q];
            int ks[4] = {p.x, p.y, p.z, p.w};
#pragma unroll
            for (int j = 0; j < 4; ++j) {
                float fk = __int_as_float(ks[j]);
                float h;
#pragma unroll
                for (int s = 0; s < 6; ++s) {
                    h = fmaxf(bv[s], fk); fk = fminf(bv[s], fk); bv[s] = h;
                }
            }
        }
        int rowG = rowBase + t;
        int* o = cand + ((size_t)(pass * NP + rowG)) * 24 + split * 6;
#pragma unroll
        for (int s = 0; s < 6; ++s)
            o[s] = colBase + (__float_as_int(bv[s]) & 0xFFF);
    }
}

// ------------------------------------------------------------------
// rescore: exact fp32 top-2 over 24 candidates per row (wave per row)
// ------------------------------------------------------------------
__global__ __launch_bounds__(256) void rescore_kernel(
    const float* __restrict__ AT, const float* __restrict__ BT,
    const int* __restrict__ cand,
    float4* __restrict__ final12,
    int* __restrict__ nn21, float* __restrict__ ratio21)
{
    const int t = threadIdx.x;
    const int w = t >> 6, l = t & 63;
    const int g = blockIdx.x * 4 + w;      // 0..32767
    const int pass = g >> 14;
    const int row = g & (NP - 1);
    const float* __restrict__ rT = pass ? BT : AT;
    const float* __restrict__ cT = pass ? AT : BT;
    float4 rv = *(const float4*)(rT + ((size_t)row << 8) + l * 4);
    float v0 = -4.f, v1 = -4.f; int i0 = 0x7fffffff, i1 = 0x7fffffff;
    const int* __restrict__ cl = cand + (size_t)g * 24;
#pragma unroll 4
    for (int j = 0; j < 24; ++j) {
        int idx = cl[j];
        float4 cv = *(const float4*)(cT + ((size_t)idx << 8) + l * 4);
        float d = rv.x * cv.x;
        d = fmaf(rv.y, cv.y, d);
        d = fmaf(rv.z, cv.z, d);
        d = fmaf(rv.w, cv.w, d);
#pragma unroll
        for (int m = 1; m < 64; m <<= 1) d += __shfl_xor(d, m, 64);
        // top-2 with lowest-index tie-break (top_k semantics)
        if (d > v0 || (d == v0 && idx < i0)) {
            v1 = v0; i1 = i0; v0 = d; i0 = idx;
        } else if (d > v1 || (d == v1 && idx < i1)) {
            v1 = d; i1 = idx;
        }
    }
    if (l == 0) {
        if (pass == 0) {
            float4 r; r.x = v0; r.y = v1;
            r.z = __int_as_float(i0); r.w = __int_as_float(i1);
            final12[row] = r;
        } else {
            nn21[row] = i0;
            float d0 = sqrtf(fmaxf(2.f - 2.f * v0, 1e-12f));
            float d1 = sqrtf(fmaxf(2.f - 2.f * v1, 1e-12f));
            ratio21[row] = d0 / (d1 + EPSF);
        }
    }
}

// ------------------------------------------------------------------
// final: mutual check, ratio test, border mask
// ------------------------------------------------------------------
__global__ void final_kernel(const float4* __restrict__ final12,
                             const int* __restrict__ nn21,
                             const float* __restrict__ ratio21,
                             float* __restrict__ out) {
    int i = blockIdx.x * blockDim.x + threadIdx.x;  // 0..16383
    float4 a = final12[i];
    float d0 = sqrtf(fmaxf(2.f - 2.f * a.x, 1e-12f));
    float d1 = sqrtf(fmaxf(2.f - 2.f * a.y, 1e-12f));
    int nn = __float_as_int(a.z);
    float r12 = d0 / (d1 + EPSF);
    bool mutual = (nn21[nn] == i);
    float r = fmaxf(r12, ratio21[nn]);
    int xA = i & (WDIM - 1), yA = i >> 7;
    int xB = nn & (WDIM - 1), yB = nn >> 7;
    bool border = (xA == 0) || (xA == WDIM - 1) || (yA == 0) || (yA == WDIM - 1) ||
                  (xB == 0) || (xB == WDIM - 1) || (yB == 0) || (yB == WDIM - 1);
    bool valid = mutual && (r < 0.95f) && !border;
    out[2 * i]       = valid ? d0 : 0.f;
    out[2 * i + 1]   = valid ? d1 : 0.f;
    out[2 * NP + i]  = (float)nn;
    out[3 * NP + i]  = valid ? 1.f : 0.f;
}

extern "C" void kernel_launch(void* const* d_in, const int* in_sizes, int n_in,
                              void* d_out, int out_size, void* d_ws, size_t ws_size,
                              hipStream_t stream) {
    (void)in_sizes; (void)n_in; (void)out_size; (void)ws_size;
    const float* A = (const float*)d_in[0];
    const float* B = (const float*)d_in[1];
    float* out = (float*)d_out;

    char* ws = (char*)d_ws;
    float* AT = (float*)ws;                              // 16 MB
    float* BT = AT + (size_t)NP * CH;                    // 16 MB
    unsigned short* Abf = (unsigned short*)(BT + (size_t)NP * CH);   // 8 MB
    unsigned short* Bbf = Abf + (size_t)NP * CH;                     // 8 MB
    int* cand = (int*)(Bbf + (size_t)NP * CH);           // 2*NP*24*4 = 3 MB
    float4* final12 = (float4*)(cand + (size_t)2 * NP * 24);  // 256 KB
    int* nn21 = (int*)(final12 + NP);                    // 64 KB
    float* ratio21 = (float*)(nn21 + NP);                // 64 KB

    prep_kernel<<<512, 256, 0, stream>>>(A, B, AT, BT, Abf, Bbf);
    simk_kernel<<<1024, 256, 0, stream>>>(Abf, Bbf, cand);
    rescore_kernel<<<8192, 256, 0, stream>>>(AT, BT, cand, final12, nn21, ratio21);
    final_kernel<<<NP / 256, 256, 0, stream>>>(final12, nn21, ratio21, out);
}

// Round 5
// 337.439 us; speedup vs baseline: 1.2016x; 1.2016x over previous
//
#include <hip/hip_runtime.h>
#include <math.h>

#define NP 16384      // pixels per map (128*128)
#define CH 256        // channels (K)
#define WDIM 128
#define EPSF 1e-8f

#define CHUNK 32              // cols per LDS chunk
#define SPLITS 4
#define COLS_PER_SPLIT (NP / SPLITS)       // 4096
#define NCHUNK (COLS_PER_SPLIT / CHUNK)    // 128
#define ROWS 256              // rows per block (4 waves x 64)
#define CHUNK_BYTES (CHUNK * CH * 2)       // 16384

typedef short short8 __attribute__((ext_vector_type(8)));
typedef float floatx4 __attribute__((ext_vector_type(4)));

typedef __attribute__((address_space(1))) const unsigned int gu32;
typedef __attribute__((address_space(3))) unsigned int lu32;

#define NEG_INF_F __int_as_float(0xFF800000)

// ------------------------------------------------------------------
// prep: per-pixel 1/||d||, write fp32 normalized transposed [pix][256]
// and bf16 normalized swizzled (element ch stored at ch ^ ((pix&7)<<3))
// ------------------------------------------------------------------
__global__ __launch_bounds__(256) void prep_kernel(
    const float* __restrict__ A, const float* __restrict__ B,
    float* __restrict__ AT, float* __restrict__ BT,
    unsigned short* __restrict__ Abf, unsigned short* __restrict__ Bbf)
{
    __shared__ float tile[64 * 257];
    __shared__ float rnv[64];
    const int bid = blockIdx.x;
    const float* __restrict__ src = (bid < 256) ? A : B;
    float* __restrict__ dstT = (bid < 256) ? AT : BT;
    unsigned short* __restrict__ dstb = (bid < 256) ? Abf : Bbf;
    const int pixBase = (bid & 255) * 64;
    const int t = threadIdx.x;

    for (int k = 0; k < 64 * 256; k += 256) {
        int idx = k + t;
        int p = idx & 63;
        int c = idx >> 6;
        tile[p * 257 + c] = src[(size_t)c * NP + pixBase + p];
    }
    __syncthreads();
    if (t < 64) {
        float s = 0.f;
        for (int c = 0; c < 256; ++c) { float v = tile[t * 257 + c]; s = fmaf(v, v, s); }
        rnv[t] = 1.0f / sqrtf(s);
    }
    __syncthreads();
    // fp32 transposed normalized
    for (int k = 0; k < 64 * 256; k += 256) {
        int idx = k + t;
        int p = idx >> 8;
        int c = idx & 255;
        dstT[((size_t)(pixBase + p) << 8) + c] = tile[p * 257 + c] * rnv[p];
    }
    // bf16 swizzled normalized (write pairs)
    for (int k = 0; k < 64 * 128; k += 256) {
        int idx = k + t;
        int p = idx >> 7;
        int c2 = (idx & 127) * 2;
        float rn = rnv[p];
        float v0 = tile[p * 257 + c2] * rn;
        float v1 = tile[p * 257 + c2 + 1] * rn;
        unsigned u0 = __float_as_uint(v0); u0 = (u0 + 0x7fffu + ((u0 >> 16) & 1u)) >> 16;
        unsigned u1 = __float_as_uint(v1); u1 = (u1 + 0x7fffu + ((u1 >> 16) & 1u)) >> 16;
        unsigned sw = ((unsigned)(p & 7)) << 3;
        int e = ((pixBase + p) << 8) + (c2 ^ (int)sw);
        *(unsigned*)(dstb + e) = (u0 & 0xffffu) | (u1 << 16);
    }
}

// ------------------------------------------------------------------
// simk: bf16 MFMA sim sweep, packed-key branchless per-lane TOP-2.
// grid 512: pass(2) x rowTile(64) x split(4). Block: 4 waves x 64 rows.
// Swapped operands: cols = M (A-operand, LDS), rows = N (B-operand, REGS,
// pinned via asm so they load from L2 exactly once per block).
// Per-lane top-2 is exact per row: each column belongs to exactly one
// lane stream, so the row's true top-2 rank <=2 within their own lane.
// key = (sim_bits & 0xFFFFF000) | col_local(12b); float-orderable.
// ------------------------------------------------------------------
__global__ __launch_bounds__(256, 2) void simk_kernel(
    const unsigned short* __restrict__ Abf, const unsigned short* __restrict__ Bbf,
    int* __restrict__ cand)
{
    __shared__ __align__(16) char smem[2 * CHUNK_BYTES];  // 32 KB
    const int bid = blockIdx.x;
    const int pass = bid >> 8;            // 0..1
    const int rt = (bid >> 2) & 63;       // 0..63
    const int split = bid & 3;
    const unsigned short* __restrict__ rows_b = pass ? Bbf : Abf;
    const unsigned short* __restrict__ cols_b = pass ? Abf : Bbf;
    const int t = threadIdx.x;
    const int w = t >> 6;
    const int l = t & 63;
    const int l15 = l & 15, lhi = l >> 4;
    const int rowBase = rt * ROWS;
    const int colBase = split * COLS_PER_SPLIT;

    // --- preload row-descriptor fragments (B-operand): 4 ni x 8 kk ---
    short8 Bfr[4][8];
#pragma unroll
    for (int ni = 0; ni < 4; ++ni) {
        int pix = rowBase + w * 64 + ni * 16 + l15;
        const unsigned short* pr = rows_b + ((size_t)pix << 8);
        int sw = (pix & 7) << 3;
#pragma unroll
        for (int kk = 0; kk < 8; ++kk) {
            int ke = kk * 32 + lhi * 8;
            Bfr[ni][kk] = *(const short8*)(pr + (ke ^ sw));
        }
    }
    // Pin each fragment: the asm result is opaque, so the compiler cannot
    // rematerialize the global load inside the chunk loop (round-3 bug).
#pragma unroll
    for (int ni = 0; ni < 4; ++ni)
#pragma unroll
        for (int kk = 0; kk < 8; ++kk)
            asm volatile("" : "+v"(Bfr[ni][kk]));

    // --- precompute LDS byte offsets for A frags (mi=0; mi=1 is +8192) ---
    int aoff[8];
    {
        int cp = l15;
        int sw = (cp & 7) << 3;
#pragma unroll
        for (int kk = 0; kk < 8; ++kk) {
            int ke = kk * 32 + lhi * 8;
            aoff[kk] = (cp * 256 + (ke ^ sw)) * 2;
        }
    }

    // packed-key top-2 per (lane, row), sorted descending
    float tv0[4], tv1[4];
#pragma unroll
    for (int ni = 0; ni < 4; ++ni) { tv0[ni] = NEG_INF_F; tv1[ni] = NEG_INF_F; }

    const char* gbase = (const char*)(cols_b + ((size_t)colBase << 8));
    const floatx4 fzero = {0.f, 0.f, 0.f, 0.f};

    // stage chunk 0
#pragma unroll
    for (int r = 0; r < 4; ++r) {
        int off = w * 4096 + r * 1024;
        __builtin_amdgcn_global_load_lds((gu32*)(gbase + off + l * 16),
                                         (lu32*)(smem + off), 16, 0, 0);
    }
    __syncthreads();

    for (int c = 0; c < NCHUNK; ++c) {
        // stage next chunk (drained by the end-of-chunk barrier)
        int nc = (c + 1 < NCHUNK) ? (c + 1) : c;
        const char* gn = gbase + (size_t)nc * CHUNK_BYTES;
        char* bufn = smem + ((c + 1) & 1) * CHUNK_BYTES;
#pragma unroll
        for (int r = 0; r < 4; ++r) {
            int off = w * 4096 + r * 1024;
            __builtin_amdgcn_global_load_lds((gu32*)(gn + off + l * 16),
                                             (lu32*)(bufn + off), 16, 0, 0);
        }

        const char* buf = smem + (c & 1) * CHUNK_BYTES;
        floatx4 acc[2][4];
        // kk = 0 peeled: accumulate from hoisted zero (no acc init movs)
        {
            short8 a0 = *(const short8*)(buf + aoff[0]);
            short8 a1 = *(const short8*)(buf + aoff[0] + 8192);
#pragma unroll
            for (int ni = 0; ni < 4; ++ni) {
                acc[0][ni] = __builtin_amdgcn_mfma_f32_16x16x32_bf16(a0, Bfr[ni][0], fzero, 0, 0, 0);
                acc[1][ni] = __builtin_amdgcn_mfma_f32_16x16x32_bf16(a1, Bfr[ni][0], fzero, 0, 0, 0);
            }
        }
#pragma unroll
        for (int kk = 1; kk < 8; ++kk) {
            short8 a0 = *(const short8*)(buf + aoff[kk]);
            short8 a1 = *(const short8*)(buf + aoff[kk] + 8192);
#pragma unroll
            for (int ni = 0; ni < 4; ++ni) {
                acc[0][ni] = __builtin_amdgcn_mfma_f32_16x16x32_bf16(a0, Bfr[ni][kk], acc[0][ni], 0, 0, 0);
                acc[1][ni] = __builtin_amdgcn_mfma_f32_16x16x32_bf16(a1, Bfr[ni][kk], acc[1][ni], 0, 0, 0);
            }
        }

        // packed-key branchless top-2: 4 VALU per value
        const int cS = c << 5;
#pragma unroll
        for (int mi = 0; mi < 2; ++mi) {
#pragma unroll
            for (int reg = 0; reg < 4; ++reg) {
                const int ib = (lhi * 4 + mi * 16 + reg) | cS;
#pragma unroll
                for (int ni = 0; ni < 4; ++ni) {
                    int kbits = (__float_as_int(acc[mi][ni][reg]) & 0xFFFFF000) | ib;
                    float fk = __int_as_float(kbits);
                    float h = fmaxf(tv0[ni], fk);
                    float lo = fminf(tv0[ni], fk);
                    tv0[ni] = h;
                    tv1[ni] = fmaxf(tv1[ni], lo);
                }
            }
        }
        __syncthreads();
    }

    // --- merge per row: 4 lanes x top2 packed keys -> top-6 per split ---
    int2* mrg = (int2*)smem;   // [256 rows][4 lhi] int2 = 8 KB
#pragma unroll
    for (int ni = 0; ni < 4; ++ni) {
        int rloc = w * 64 + ni * 16 + l15;
        int2 p;
        p.x = __float_as_int(tv0[ni]);
        p.y = __float_as_int(tv1[ni]);
        mrg[rloc * 4 + lhi] = p;
    }
    __syncthreads();
    {
        float bv[6];
#pragma unroll
        for (int s = 0; s < 6; ++s) bv[s] = NEG_INF_F;
#pragma unroll
        for (int q = 0; q < 4; ++q) {
            int2 p = mrg[t * 4 + q];
            int ks[2] = {p.x, p.y};
#pragma unroll
            for (int j = 0; j < 2; ++j) {
                float fk = __int_as_float(ks[j]);
                float h;
#pragma unroll
                for (int s = 0; s < 6; ++s) {
                    h = fmaxf(bv[s], fk); fk = fminf(bv[s], fk); bv[s] = h;
                }
            }
        }
        int rowG = rowBase + t;
        int* o = cand + ((size_t)(pass * NP + rowG)) * 24 + split * 6;
#pragma unroll
        for (int s = 0; s < 6; ++s)
            o[s] = colBase + (__float_as_int(bv[s]) & 0xFFF);
    }
}

// ------------------------------------------------------------------
// rescore: exact fp32 top-2 over 24 candidates per row (wave per row)
// ------------------------------------------------------------------
__global__ __launch_bounds__(256) void rescore_kernel(
    const float* __restrict__ AT, const float* __restrict__ BT,
    const int* __restrict__ cand,
    float4* __restrict__ final12,
    int* __restrict__ nn21, float* __restrict__ ratio21)
{
    const int t = threadIdx.x;
    const int w = t >> 6, l = t & 63;
    const int g = blockIdx.x * 4 + w;      // 0..32767
    const int pass = g >> 14;
    const int row = g & (NP - 1);
    const float* __restrict__ rT = pass ? BT : AT;
    const float* __restrict__ cT = pass ? AT : BT;
    float4 rv = *(const float4*)(rT + ((size_t)row << 8) + l * 4);
    float v0 = -4.f, v1 = -4.f; int i0 = 0x7fffffff, i1 = 0x7fffffff;
    const int* __restrict__ cl = cand + (size_t)g * 24;
#pragma unroll 4
    for (int j = 0; j < 24; ++j) {
        int idx = cl[j];
        float4 cv = *(const float4*)(cT + ((size_t)idx << 8) + l * 4);
        float d = rv.x * cv.x;
        d = fmaf(rv.y, cv.y, d);
        d = fmaf(rv.z, cv.z, d);
        d = fmaf(rv.w, cv.w, d);
#pragma unroll
        for (int m = 1; m < 64; m <<= 1) d += __shfl_xor(d, m, 64);
        // top-2 with lowest-index tie-break (top_k semantics)
        if (d > v0 || (d == v0 && idx < i0)) {
            v1 = v0; i1 = i0; v0 = d; i0 = idx;
        } else if (d > v1 || (d == v1 && idx < i1)) {
            v1 = d; i1 = idx;
        }
    }
    if (l == 0) {
        if (pass == 0) {
            float4 r; r.x = v0; r.y = v1;
            r.z = __int_as_float(i0); r.w = __int_as_float(i1);
            final12[row] = r;
        } else {
            nn21[row] = i0;
            float d0 = sqrtf(fmaxf(2.f - 2.f * v0, 1e-12f));
            float d1 = sqrtf(fmaxf(2.f - 2.f * v1, 1e-12f));
            ratio21[row] = d0 / (d1 + EPSF);
        }
    }
}

// ------------------------------------------------------------------
// final: mutual check, ratio test, border mask
// ------------------------------------------------------------------
__global__ void final_kernel(const float4* __restrict__ final12,
                             const int* __restrict__ nn21,
                             const float* __restrict__ ratio21,
                             float* __restrict__ out) {
    int i = blockIdx.x * blockDim.x + threadIdx.x;  // 0..16383
    float4 a = final12[i];
    float d0 = sqrtf(fmaxf(2.f - 2.f * a.x, 1e-12f));
    float d1 = sqrtf(fmaxf(2.f - 2.f * a.y, 1e-12f));
    int nn = __float_as_int(a.z);
    float r12 = d0 / (d1 + EPSF);
    bool mutual = (nn21[nn] == i);
    float r = fmaxf(r12, ratio21[nn]);
    int xA = i & (WDIM - 1), yA = i >> 7;
    int xB = nn & (WDIM - 1), yB = nn >> 7;
    bool border = (xA == 0) || (xA == WDIM - 1) || (yA == 0) || (yA == WDIM - 1) ||
                  (xB == 0) || (xB == WDIM - 1) || (yB == 0) || (yB == WDIM - 1);
    bool valid = mutual && (r < 0.95f) && !border;
    out[2 * i]       = valid ? d0 : 0.f;
    out[2 * i + 1]   = valid ? d1 : 0.f;
    out[2 * NP + i]  = (float)nn;
    out[3 * NP + i]  = valid ? 1.f : 0.f;
}

extern "C" void kernel_launch(void* const* d_in, const int* in_sizes, int n_in,
                              void* d_out, int out_size, void* d_ws, size_t ws_size,
                              hipStream_t stream) {
    (void)in_sizes; (void)n_in; (void)out_size; (void)ws_size;
    const float* A = (const float*)d_in[0];
    const float* B = (const float*)d_in[1];
    float* out = (float*)d_out;

    char* ws = (char*)d_ws;
    float* AT = (float*)ws;                              // 16 MB
    float* BT = AT + (size_t)NP * CH;                    // 16 MB
    unsigned short* Abf = (unsigned short*)(BT + (size_t)NP * CH);   // 8 MB
    unsigned short* Bbf = Abf + (size_t)NP * CH;                     // 8 MB
    int* cand = (int*)(Bbf + (size_t)NP * CH);           // 2*NP*24*4 = 3 MB
    float4* final12 = (float4*)(cand + (size_t)2 * NP * 24);  // 256 KB
    int* nn21 = (int*)(final12 + NP);                    // 64 KB
    float* ratio21 = (float*)(nn21 + NP);                // 64 KB

    prep_kernel<<<512, 256, 0, stream>>>(A, B, AT, BT, Abf, Bbf);
    simk_kernel<<<512, 256, 0, stream>>>(Abf, Bbf, cand);
    rescore_kernel<<<8192, 256, 0, stream>>>(AT, BT, cand, final12, nn21, ratio21);
    final_kernel<<<NP / 256, 256, 0, stream>>>(final12, nn21, ratio21, out);
}

// Round 6
// 336.846 us; speedup vs baseline: 1.2037x; 1.0018x over previous
//
#include <hip/hip_runtime.h>
#include <math.h>

#define NP 16384      // pixels per map (128*128)
#define CH 256        // channels (K)
#define WDIM 128
#define EPSF 1e-8f

#define CHUNK 32              // cols per LDS chunk
#define SPLITS 4
#define COLS_PER_SPLIT (NP / SPLITS)       // 4096
#define NCHUNK (COLS_PER_SPLIT / CHUNK)    // 128
#define ROWS 256              // rows per block (4 waves x 64)
#define CHUNK_BYTES (CHUNK * CH * 2)       // 16384

typedef short short8 __attribute__((ext_vector_type(8)));
typedef float floatx4 __attribute__((ext_vector_type(4)));

typedef __attribute__((address_space(1))) const unsigned int gu32;
typedef __attribute__((address_space(3))) unsigned int lu32;

#define NEG_INF_F __int_as_float(0xFF800000)

// ------------------------------------------------------------------
// prep: per-pixel 1/||d||, write fp32 normalized transposed [pix][256]
// and bf16 normalized swizzled (element ch stored at ch ^ ((pix&7)<<3))
// ------------------------------------------------------------------
__global__ __launch_bounds__(256) void prep_kernel(
    const float* __restrict__ A, const float* __restrict__ B,
    float* __restrict__ AT, float* __restrict__ BT,
    unsigned short* __restrict__ Abf, unsigned short* __restrict__ Bbf)
{
    __shared__ float tile[64 * 257];
    __shared__ float rnv[64];
    const int bid = blockIdx.x;
    const float* __restrict__ src = (bid < 256) ? A : B;
    float* __restrict__ dstT = (bid < 256) ? AT : BT;
    unsigned short* __restrict__ dstb = (bid < 256) ? Abf : Bbf;
    const int pixBase = (bid & 255) * 64;
    const int t = threadIdx.x;

    for (int k = 0; k < 64 * 256; k += 256) {
        int idx = k + t;
        int p = idx & 63;
        int c = idx >> 6;
        tile[p * 257 + c] = src[(size_t)c * NP + pixBase + p];
    }
    __syncthreads();
    if (t < 64) {
        float s = 0.f;
        for (int c = 0; c < 256; ++c) { float v = tile[t * 257 + c]; s = fmaf(v, v, s); }
        rnv[t] = 1.0f / sqrtf(s);
    }
    __syncthreads();
    // fp32 transposed normalized
    for (int k = 0; k < 64 * 256; k += 256) {
        int idx = k + t;
        int p = idx >> 8;
        int c = idx & 255;
        dstT[((size_t)(pixBase + p) << 8) + c] = tile[p * 257 + c] * rnv[p];
    }
    // bf16 swizzled normalized (write pairs)
    for (int k = 0; k < 64 * 128; k += 256) {
        int idx = k + t;
        int p = idx >> 7;
        int c2 = (idx & 127) * 2;
        float rn = rnv[p];
        float v0 = tile[p * 257 + c2] * rn;
        float v1 = tile[p * 257 + c2 + 1] * rn;
        unsigned u0 = __float_as_uint(v0); u0 = (u0 + 0x7fffu + ((u0 >> 16) & 1u)) >> 16;
        unsigned u1 = __float_as_uint(v1); u1 = (u1 + 0x7fffu + ((u1 >> 16) & 1u)) >> 16;
        unsigned sw = ((unsigned)(p & 7)) << 3;
        int e = ((pixBase + p) << 8) + (c2 ^ (int)sw);
        *(unsigned*)(dstb + e) = (u0 & 0xffffu) | (u1 << 16);
    }
}

// ------------------------------------------------------------------
// simk: bf16 MFMA sim sweep, packed-key branchless per-lane TOP-2,
// SOFTWARE-PIPELINED: top-2 update of chunk c-1 overlaps the in-flight
// MFMAs of chunk c (ping-pong accA/accB, all indices compile-time).
// grid 512: pass(2) x rowTile(64) x split(4). Block: 4 waves x 64 rows.
// Swapped operands: cols = M (A-operand, LDS), rows = N (B-operand, REGS,
// pinned via asm so they load from L2 exactly once per block).
// key = (sim_bits & 0xFFFFF000) | col_local(12b); float-orderable.
// ------------------------------------------------------------------
__global__ __launch_bounds__(256, 2) void simk_kernel(
    const unsigned short* __restrict__ Abf, const unsigned short* __restrict__ Bbf,
    int* __restrict__ cand)
{
    __shared__ __align__(16) char smem[2 * CHUNK_BYTES];  // 32 KB
    const int bid = blockIdx.x;
    const int pass = bid >> 8;            // 0..1
    const int rt = (bid >> 2) & 63;       // 0..63
    const int split = bid & 3;
    const unsigned short* __restrict__ rows_b = pass ? Bbf : Abf;
    const unsigned short* __restrict__ cols_b = pass ? Abf : Bbf;
    const int t = threadIdx.x;
    const int w = t >> 6;
    const int l = t & 63;
    const int l15 = l & 15, lhi = l >> 4;
    const int rowBase = rt * ROWS;
    const int colBase = split * COLS_PER_SPLIT;

    // --- preload row-descriptor fragments (B-operand): 4 ni x 8 kk ---
    short8 Bfr[4][8];
#pragma unroll
    for (int ni = 0; ni < 4; ++ni) {
        int pix = rowBase + w * 64 + ni * 16 + l15;
        const unsigned short* pr = rows_b + ((size_t)pix << 8);
        int sw = (pix & 7) << 3;
#pragma unroll
        for (int kk = 0; kk < 8; ++kk) {
            int ke = kk * 32 + lhi * 8;
            Bfr[ni][kk] = *(const short8*)(pr + (ke ^ sw));
        }
    }
    // Pin each fragment: asm result is opaque -> no per-chunk remat.
#pragma unroll
    for (int ni = 0; ni < 4; ++ni)
#pragma unroll
        for (int kk = 0; kk < 8; ++kk)
            asm volatile("" : "+v"(Bfr[ni][kk]));

    // --- precompute LDS byte offsets for A frags (mi=0; mi=1 is +8192) ---
    int aoff[8];
    {
        int cp = l15;
        int sw = (cp & 7) << 3;
#pragma unroll
        for (int kk = 0; kk < 8; ++kk) {
            int ke = kk * 32 + lhi * 8;
            aoff[kk] = (cp * 256 + (ke ^ sw)) * 2;
        }
    }

    // packed-key top-2 per (lane, row), sorted descending
    float tv0[4], tv1[4];
#pragma unroll
    for (int ni = 0; ni < 4; ++ni) { tv0[ni] = NEG_INF_F; tv1[ni] = NEG_INF_F; }

    const char* gbase = (const char*)(cols_b + ((size_t)colBase << 8));
    const floatx4 fzero = {0.f, 0.f, 0.f, 0.f};

    floatx4 accA[2][4], accB[2][4];

#define STAGE(CIDX, BUFSEL) do {                                              \
        const char* gsrc_ = gbase + (size_t)(CIDX) * CHUNK_BYTES;             \
        char* bdst_ = smem + (BUFSEL) * CHUNK_BYTES;                          \
        _Pragma("unroll")                                                     \
        for (int r_ = 0; r_ < 4; ++r_) {                                      \
            int off_ = w * 4096 + r_ * 1024;                                  \
            __builtin_amdgcn_global_load_lds((gu32*)(gsrc_ + off_ + l * 16),  \
                                             (lu32*)(bdst_ + off_), 16, 0, 0);\
        }                                                                     \
    } while (0)

#define COMPUTE(ACC, BUFSEL) do {                                             \
        const char* buf_ = smem + (BUFSEL) * CHUNK_BYTES;                     \
        {                                                                     \
            short8 a0_ = *(const short8*)(buf_ + aoff[0]);                    \
            short8 a1_ = *(const short8*)(buf_ + aoff[0] + 8192);             \
            _Pragma("unroll")                                                 \
            for (int ni_ = 0; ni_ < 4; ++ni_) {                               \
                ACC[0][ni_] = __builtin_amdgcn_mfma_f32_16x16x32_bf16(a0_, Bfr[ni_][0], fzero, 0, 0, 0); \
                ACC[1][ni_] = __builtin_amdgcn_mfma_f32_16x16x32_bf16(a1_, Bfr[ni_][0], fzero, 0, 0, 0); \
            }                                                                 \
        }                                                                     \
        _Pragma("unroll")                                                     \
        for (int kk_ = 1; kk_ < 8; ++kk_) {                                   \
            short8 a0_ = *(const short8*)(buf_ + aoff[kk_]);                  \
            short8 a1_ = *(const short8*)(buf_ + aoff[kk_] + 8192);           \
            _Pragma("unroll")                                                 \
            for (int ni_ = 0; ni_ < 4; ++ni_) {                               \
                ACC[0][ni_] = __builtin_amdgcn_mfma_f32_16x16x32_bf16(a0_, Bfr[ni_][kk_], ACC[0][ni_], 0, 0, 0); \
                ACC[1][ni_] = __builtin_amdgcn_mfma_f32_16x16x32_bf16(a1_, Bfr[ni_][kk_], ACC[1][ni_], 0, 0, 0); \
            }                                                                 \
        }                                                                     \
    } while (0)

#define TOPK(ACC, CIDX) do {                                                  \
        const int cS_ = (CIDX) << 5;                                          \
        _Pragma("unroll")                                                     \
        for (int mi_ = 0; mi_ < 2; ++mi_) {                                   \
            _Pragma("unroll")                                                 \
            for (int reg_ = 0; reg_ < 4; ++reg_) {                            \
                const int ib_ = (lhi * 4 + mi_ * 16 + reg_) | cS_;            \
                _Pragma("unroll")                                             \
                for (int ni_ = 0; ni_ < 4; ++ni_) {                           \
                    int kb_ = (__float_as_int(ACC[mi_][ni_][reg_]) & 0xFFFFF000) | ib_; \
                    float fk_ = __int_as_float(kb_);                          \
                    float h_ = fmaxf(tv0[ni_], fk_);                          \
                    float lo_ = fminf(tv0[ni_], fk_);                         \
                    tv0[ni_] = h_;                                            \
                    tv1[ni_] = fmaxf(tv1[ni_], lo_);                          \
                }                                                             \
            }                                                                 \
        }                                                                     \
    } while (0)

    // prologue: chunk 0 staged+computed; chunk 1 staging in flight
    STAGE(0, 0);
    __syncthreads();
    STAGE(1, 1);
    COMPUTE(accA, 0);

    // steady state: compute chunk cc while top-2-ing chunk cc-1
    for (int cc = 1; cc < NCHUNK - 1; cc += 2) {
        __syncthreads();                 // chunk cc staged
        STAGE(cc + 1, (cc + 1) & 1);
        COMPUTE(accB, cc & 1);
        TOPK(accA, cc - 1);
        __syncthreads();                 // chunk cc+1 staged
        STAGE(cc + 2, (cc + 2) & 1);
        COMPUTE(accA, (cc + 1) & 1);
        TOPK(accB, cc);
    }
    // tail: chunk NCHUNK-1 (odd)
    __syncthreads();
    COMPUTE(accB, (NCHUNK - 1) & 1);
    TOPK(accA, NCHUNK - 2);
    TOPK(accB, NCHUNK - 1);

#undef STAGE
#undef COMPUTE
#undef TOPK

    // --- merge per row: 4 lanes x top2 packed keys -> top-6 per split ---
    __syncthreads();
    int2* mrg = (int2*)smem;   // [256 rows][4 lhi] int2 = 8 KB
#pragma unroll
    for (int ni = 0; ni < 4; ++ni) {
        int rloc = w * 64 + ni * 16 + l15;
        int2 p;
        p.x = __float_as_int(tv0[ni]);
        p.y = __float_as_int(tv1[ni]);
        mrg[rloc * 4 + lhi] = p;
    }
    __syncthreads();
    {
        float bv[6];
#pragma unroll
        for (int s = 0; s < 6; ++s) bv[s] = NEG_INF_F;
#pragma unroll
        for (int q = 0; q < 4; ++q) {
            int2 p = mrg[t * 4 + q];
            int ks[2] = {p.x, p.y};
#pragma unroll
            for (int j = 0; j < 2; ++j) {
                float fk = __int_as_float(ks[j]);
                float h;
#pragma unroll
                for (int s = 0; s < 6; ++s) {
                    h = fmaxf(bv[s], fk); fk = fminf(bv[s], fk); bv[s] = h;
                }
            }
        }
        int rowG = rowBase + t;
        int* o = cand + ((size_t)(pass * NP + rowG)) * 24 + split * 6;
#pragma unroll
        for (int s = 0; s < 6; ++s)
            o[s] = colBase + (__float_as_int(bv[s]) & 0xFFF);
    }
}

// ------------------------------------------------------------------
// rescore: exact fp32 top-2 over 24 candidates per row (wave per row)
// ------------------------------------------------------------------
__global__ __launch_bounds__(256) void rescore_kernel(
    const float* __restrict__ AT, const float* __restrict__ BT,
    const int* __restrict__ cand,
    float4* __restrict__ final12,
    int* __restrict__ nn21, float* __restrict__ ratio21)
{
    const int t = threadIdx.x;
    const int w = t >> 6, l = t & 63;
    const int g = blockIdx.x * 4 + w;      // 0..32767
    const int pass = g >> 14;
    const int row = g & (NP - 1);
    const float* __restrict__ rT = pass ? BT : AT;
    const float* __restrict__ cT = pass ? AT : BT;
    float4 rv = *(const float4*)(rT + ((size_t)row << 8) + l * 4);
    float v0 = -4.f, v1 = -4.f; int i0 = 0x7fffffff, i1 = 0x7fffffff;
    const int* __restrict__ cl = cand + (size_t)g * 24;
#pragma unroll 4
    for (int j = 0; j < 24; ++j) {
        int idx = cl[j];
        float4 cv = *(const float4*)(cT + ((size_t)idx << 8) + l * 4);
        float d = rv.x * cv.x;
        d = fmaf(rv.y, cv.y, d);
        d = fmaf(rv.z, cv.z, d);
        d = fmaf(rv.w, cv.w, d);
#pragma unroll
        for (int m = 1; m < 64; m <<= 1) d += __shfl_xor(d, m, 64);
        // top-2 with lowest-index tie-break (top_k semantics)
        if (d > v0 || (d == v0 && idx < i0)) {
            v1 = v0; i1 = i0; v0 = d; i0 = idx;
        } else if (d > v1 || (d == v1 && idx < i1)) {
            v1 = d; i1 = idx;
        }
    }
    if (l == 0) {
        if (pass == 0) {
            float4 r; r.x = v0; r.y = v1;
            r.z = __int_as_float(i0); r.w = __int_as_float(i1);
            final12[row] = r;
        } else {
            nn21[row] = i0;
            float d0 = sqrtf(fmaxf(2.f - 2.f * v0, 1e-12f));
            float d1 = sqrtf(fmaxf(2.f - 2.f * v1, 1e-12f));
            ratio21[row] = d0 / (d1 + EPSF);
        }
    }
}

// ------------------------------------------------------------------
// final: mutual check, ratio test, border mask
// ------------------------------------------------------------------
__global__ void final_kernel(const float4* __restrict__ final12,
                             const int* __restrict__ nn21,
                             const float* __restrict__ ratio21,
                             float* __restrict__ out) {
    int i = blockIdx.x * blockDim.x + threadIdx.x;  // 0..16383
    float4 a = final12[i];
    float d0 = sqrtf(fmaxf(2.f - 2.f * a.x, 1e-12f));
    float d1 = sqrtf(fmaxf(2.f - 2.f * a.y, 1e-12f));
    int nn = __float_as_int(a.z);
    float r12 = d0 / (d1 + EPSF);
    bool mutual = (nn21[nn] == i);
    float r = fmaxf(r12, ratio21[nn]);
    int xA = i & (WDIM - 1), yA = i >> 7;
    int xB = nn & (WDIM - 1), yB = nn >> 7;
    bool border = (xA == 0) || (xA == WDIM - 1) || (yA == 0) || (yA == WDIM - 1) ||
                  (xB == 0) || (xB == WDIM - 1) || (yB == 0) || (yB == WDIM - 1);
    bool valid = mutual && (r < 0.95f) && !border;
    out[2 * i]       = valid ? d0 : 0.f;
    out[2 * i + 1]   = valid ? d1 : 0.f;
    out[2 * NP + i]  = (float)nn;
    out[3 * NP + i]  = valid ? 1.f : 0.f;
}

extern "C" void kernel_launch(void* const* d_in, const int* in_sizes, int n_in,
                              void* d_out, int out_size, void* d_ws, size_t ws_size,
                              hipStream_t stream) {
    (void)in_sizes; (void)n_in; (void)out_size; (void)ws_size;
    const float* A = (const float*)d_in[0];
    const float* B = (const float*)d_in[1];
    float* out = (float*)d_out;

    char* ws = (char*)d_ws;
    float* AT = (float*)ws;                              // 16 MB
    float* BT = AT + (size_t)NP * CH;                    // 16 MB
    unsigned short* Abf = (unsigned short*)(BT + (size_t)NP * CH);   // 8 MB
    unsigned short* Bbf = Abf + (size_t)NP * CH;                     // 8 MB
    int* cand = (int*)(Bbf + (size_t)NP * CH);           // 2*NP*24*4 = 3 MB
    float4* final12 = (float4*)(cand + (size_t)2 * NP * 24);  // 256 KB
    int* nn21 = (int*)(final12 + NP);                    // 64 KB
    float* ratio21 = (float*)(nn21 + NP);                // 64 KB

    prep_kernel<<<512, 256, 0, stream>>>(A, B, AT, BT, Abf, Bbf);
    simk_kernel<<<512, 256, 0, stream>>>(Abf, Bbf, cand);
    rescore_kernel<<<8192, 256, 0, stream>>>(AT, BT, cand, final12, nn21, ratio21);
    final_kernel<<<NP / 256, 256, 0, stream>>>(final12, nn21, ratio21, out);
}

// Round 7
// 315.306 us; speedup vs baseline: 1.2860x; 1.0683x over previous
//
#include <hip/hip_runtime.h>
#include <math.h>

#define NP 16384      // pixels per map (128*128)
#define CH 256        // channels (K)
#define WDIM 128
#define EPSF 1e-8f

#define CHUNK 32
#define SPLITS 8
#define CPS (NP / SPLITS)            // 2048 cols per split
#define NCHUNK (CPS / CHUNK)         // 64
#define ROWS 256                     // rows per block (4 waves x 64)
#define NRT (NP / ROWS)              // 64 row tiles
#define CHUNK_BYTES (CHUNK * CH * 2) // 16384
#define NCOLSLOT (NRT * 3)           // 192 col-candidate slots per column

typedef short short8 __attribute__((ext_vector_type(8)));
typedef float floatx4 __attribute__((ext_vector_type(4)));

typedef __attribute__((address_space(1))) const unsigned int gu32;
typedef __attribute__((address_space(3))) unsigned int lu32;

#define NEG_INF_F __int_as_float(0xFF800000)

// ------------------------------------------------------------------
// prep: per-pixel 1/||d||, fp32 normalized transposed [pix][256],
// bf16 normalized swizzled (element ch stored at ch ^ ((pix&7)<<3))
// ------------------------------------------------------------------
__global__ __launch_bounds__(256) void prep_kernel(
    const float* __restrict__ A, const float* __restrict__ B,
    float* __restrict__ AT, float* __restrict__ BT,
    unsigned short* __restrict__ Abf, unsigned short* __restrict__ Bbf)
{
    __shared__ float tile[64 * 257];
    __shared__ float rnv[64];
    const int bid = blockIdx.x;
    const float* __restrict__ src = (bid < 256) ? A : B;
    float* __restrict__ dstT = (bid < 256) ? AT : BT;
    unsigned short* __restrict__ dstb = (bid < 256) ? Abf : Bbf;
    const int pixBase = (bid & 255) * 64;
    const int t = threadIdx.x;

    for (int k = 0; k < 64 * 256; k += 256) {
        int idx = k + t;
        int p = idx & 63;
        int c = idx >> 6;
        tile[p * 257 + c] = src[(size_t)c * NP + pixBase + p];
    }
    __syncthreads();
    if (t < 64) {
        float s = 0.f;
        for (int c = 0; c < 256; ++c) { float v = tile[t * 257 + c]; s = fmaf(v, v, s); }
        rnv[t] = 1.0f / sqrtf(s);
    }
    __syncthreads();
    for (int k = 0; k < 64 * 256; k += 256) {
        int idx = k + t;
        int p = idx >> 8;
        int c = idx & 255;
        dstT[((size_t)(pixBase + p) << 8) + c] = tile[p * 257 + c] * rnv[p];
    }
    for (int k = 0; k < 64 * 128; k += 256) {
        int idx = k + t;
        int p = idx >> 7;
        int c2 = (idx & 127) * 2;
        float rn = rnv[p];
        float v0 = tile[p * 257 + c2] * rn;
        float v1 = tile[p * 257 + c2 + 1] * rn;
        unsigned u0 = __float_as_uint(v0); u0 = (u0 + 0x7fffu + ((u0 >> 16) & 1u)) >> 16;
        unsigned u1 = __float_as_uint(v1); u1 = (u1 + 0x7fffu + ((u1 >> 16) & 1u)) >> 16;
        unsigned sw = ((unsigned)(p & 7)) << 3;
        int e = ((pixBase + p) << 8) + (c2 ^ (int)sw);
        *(unsigned*)(dstb + e) = (u0 & 0xffffu) | (u1 << 16);
    }
}

// ------------------------------------------------------------------
// simk ONE-PASS: bf16 MFMA sim sweep; per chunk extracts BOTH
//  - row running top-2 per lane (packed key | col-local 11b)
//  - column top-3 per block via LDS hierarchical merge
//    (key = sim_bits & 0xFFFFF000 | block-local row 8b)
// grid 512 = rowTile(64) x split(8). Block: 4 waves x 64 rows x 2048 cols.
// Rows (A) = B-operand in regs (pinned); cols (B) staged in LDS.
// ------------------------------------------------------------------
__global__ __launch_bounds__(256, 2) void simk_kernel(
    const unsigned short* __restrict__ Abf, const unsigned short* __restrict__ Bbf,
    int* __restrict__ cand_row, unsigned* __restrict__ cand_col)
{
    __shared__ __align__(16) char smem[2 * CHUNK_BYTES];            // 32 KB staging
    __shared__ __align__(16) unsigned colbufU[32 * 128 + 32 * 16];  // 18 KB col merge
    const int bid = blockIdx.x;
    const int rt = bid >> 3;
    const int split = bid & 7;
    const int t = threadIdx.x;
    const int w = t >> 6;
    const int l = t & 63;
    const int l15 = l & 15, lhi = l >> 4;
    const int rowBase = rt * ROWS;
    const int colBase = split * CPS;

    // --- row-descriptor fragments (B-operand) from A, pinned ---
    short8 Bfr[4][8];
#pragma unroll
    for (int ni = 0; ni < 4; ++ni) {
        int pix = rowBase + w * 64 + ni * 16 + l15;
        const unsigned short* pr = Abf + ((size_t)pix << 8);
        int sw = (pix & 7) << 3;
#pragma unroll
        for (int kk = 0; kk < 8; ++kk) {
            int ke = kk * 32 + lhi * 8;
            Bfr[ni][kk] = *(const short8*)(pr + (ke ^ sw));
        }
    }
#pragma unroll
    for (int ni = 0; ni < 4; ++ni)
#pragma unroll
        for (int kk = 0; kk < 8; ++kk)
            asm volatile("" : "+v"(Bfr[ni][kk]));

    // --- LDS byte offsets for A-operand frags (mi=0; mi=1 is +8192) ---
    int aoff[8];
    {
        int cp = l15;
        int sw = (cp & 7) << 3;
#pragma unroll
        for (int kk = 0; kk < 8; ++kk) {
            int ke = kk * 32 + lhi * 8;
            aoff[kk] = (cp * 256 + (ke ^ sw)) * 2;
        }
    }

    float tv0[4], tv1[4];
#pragma unroll
    for (int ni = 0; ni < 4; ++ni) { tv0[ni] = NEG_INF_F; tv1[ni] = NEG_INF_F; }

    const char* gbase = (const char*)(Bbf + ((size_t)colBase << 8));
    const floatx4 fzero = {0.f, 0.f, 0.f, 0.f};
    floatx4 acc[2][4];

#define STAGE(CIDX, BUFSEL) do {                                              \
        const char* gsrc_ = gbase + (size_t)(CIDX) * CHUNK_BYTES;             \
        char* bdst_ = smem + (BUFSEL) * CHUNK_BYTES;                          \
        _Pragma("unroll")                                                     \
        for (int r_ = 0; r_ < 4; ++r_) {                                      \
            int off_ = w * 4096 + r_ * 1024;                                  \
            __builtin_amdgcn_global_load_lds((gu32*)(gsrc_ + off_ + l * 16),  \
                                             (lu32*)(bdst_ + off_), 16, 0, 0);\
        }                                                                     \
    } while (0)

    STAGE(0, 0);

    for (int c = 0; c < NCHUNK; ++c) {
        __syncthreads();                       // chunk c staged; colbuf free
        if (c + 1 < NCHUNK) STAGE(c + 1, (c + 1) & 1);

        // ---- COMPUTE: 64 MFMA into acc ----
        {
            const char* buf = smem + (c & 1) * CHUNK_BYTES;
            __builtin_amdgcn_s_setprio(1);
            {
                short8 a0 = *(const short8*)(buf + aoff[0]);
                short8 a1 = *(const short8*)(buf + aoff[0] + 8192);
#pragma unroll
                for (int ni = 0; ni < 4; ++ni) {
                    acc[0][ni] = __builtin_amdgcn_mfma_f32_16x16x32_bf16(a0, Bfr[ni][0], fzero, 0, 0, 0);
                    acc[1][ni] = __builtin_amdgcn_mfma_f32_16x16x32_bf16(a1, Bfr[ni][0], fzero, 0, 0, 0);
                }
            }
#pragma unroll
            for (int kk = 1; kk < 8; ++kk) {
                short8 a0 = *(const short8*)(buf + aoff[kk]);
                short8 a1 = *(const short8*)(buf + aoff[kk] + 8192);
#pragma unroll
                for (int ni = 0; ni < 4; ++ni) {
                    acc[0][ni] = __builtin_amdgcn_mfma_f32_16x16x32_bf16(a0, Bfr[ni][kk], acc[0][ni], 0, 0, 0);
                    acc[1][ni] = __builtin_amdgcn_mfma_f32_16x16x32_bf16(a1, Bfr[ni][kk], acc[1][ni], 0, 0, 0);
                }
            }
            __builtin_amdgcn_s_setprio(0);
        }

        // ---- COL per-lane: top-2 of 4 rows per (mi,reg) stream -> LDS ----
        {
            const unsigned brb = ((unsigned)w << 6) | (unsigned)l15;
#pragma unroll
            for (int mi = 0; mi < 2; ++mi) {
#pragma unroll
                for (int reg = 0; reg < 4; ++reg) {
                    unsigned k0 = (__float_as_uint(acc[mi][0][reg]) & 0xFFFFF000u) | brb;
                    unsigned k1 = (__float_as_uint(acc[mi][1][reg]) & 0xFFFFF000u) | (brb | 16u);
                    unsigned k2 = (__float_as_uint(acc[mi][2][reg]) & 0xFFFFF000u) | (brb | 32u);
                    unsigned k3 = (__float_as_uint(acc[mi][3][reg]) & 0xFFFFF000u) | (brb | 48u);
                    float f0 = __uint_as_float(k0), f1 = __uint_as_float(k1);
                    float f2 = __uint_as_float(k2), f3 = __uint_as_float(k3);
                    float h01 = fmaxf(f0, f1), l01 = fminf(f0, f1);
                    float h23 = fmaxf(f2, f3), l23 = fminf(f2, f3);
                    float top = fmaxf(h01, h23);
                    float sec = fmaxf(fminf(h01, h23), fmaxf(l01, l23));
                    int colL = mi * 16 + lhi * 4 + reg;
                    *(float2*)&colbufU[colL * 128 + w * 32 + l15 * 2] = make_float2(top, sec);
                }
            }
        }

        // ---- ROW top-2 (packed key | c*32 + col-local) ----
        {
            const int cS = c << 5;
#pragma unroll
            for (int mi = 0; mi < 2; ++mi) {
#pragma unroll
                for (int reg = 0; reg < 4; ++reg) {
                    const int ib = (lhi * 4 + mi * 16 + reg) | cS;
#pragma unroll
                    for (int ni = 0; ni < 4; ++ni) {
                        int kbits = (__float_as_int(acc[mi][ni][reg]) & 0xFFFFF000) | ib;
                        float fk = __int_as_float(kbits);
                        float h = fmaxf(tv0[ni], fk);
                        float lo = fminf(tv0[ni], fk);
                        tv0[ni] = h;
                        tv1[ni] = fmaxf(tv1[ni], lo);
                    }
                }
            }
        }

        __syncthreads();                       // colbuf complete
        // ---- merge1: 256 threads, (col, oct): top-2 of 16 keys ----
        {
            int colL = t >> 3, oct = t & 7;
            const float4* p = (const float4*)&colbufU[colL * 128 + oct * 16];
            float a = NEG_INF_F, b = NEG_INF_F;
#pragma unroll
            for (int q = 0; q < 4; ++q) {
                float4 v = p[q];
                float h, lo;
                h = fmaxf(a, v.x); lo = fminf(a, v.x); a = h; b = fmaxf(b, lo);
                h = fmaxf(a, v.y); lo = fminf(a, v.y); a = h; b = fmaxf(b, lo);
                h = fmaxf(a, v.z); lo = fminf(a, v.z); a = h; b = fmaxf(b, lo);
                h = fmaxf(a, v.w); lo = fminf(a, v.w); a = h; b = fmaxf(b, lo);
            }
            *(float2*)&colbufU[32 * 128 + colL * 16 + oct * 2] = make_float2(a, b);
        }
        __syncthreads();                       // colbuf2 complete
        // ---- merge2: 32 threads: top-3 of 16 -> global cand_col ----
        if (t < 32) {
            const float4* p = (const float4*)&colbufU[32 * 128 + t * 16];
            float b0 = NEG_INF_F, b1 = NEG_INF_F, b2 = NEG_INF_F;
#pragma unroll
            for (int q = 0; q < 4; ++q) {
                float4 v = p[q];
                float vv[4] = {v.x, v.y, v.z, v.w};
#pragma unroll
                for (int j = 0; j < 4; ++j) {
                    float k = vv[j], h;
                    h = fmaxf(b0, k); k = fminf(b0, k); b0 = h;
                    h = fmaxf(b1, k); k = fminf(b1, k); b1 = h;
                    b2 = fmaxf(b2, k);
                }
            }
            int colG = colBase + c * 32 + t;
            cand_col[(size_t)(rt * 3 + 0) * NP + colG] = __float_as_uint(b0);
            cand_col[(size_t)(rt * 3 + 1) * NP + colG] = __float_as_uint(b1);
            cand_col[(size_t)(rt * 3 + 2) * NP + colG] = __float_as_uint(b2);
        }
    }
#undef STAGE

    // ---- final row merge: 4 lanes x top2 -> top-3 per split ----
    __syncthreads();
    int2* mrg = (int2*)colbufU;   // [256 rows][4 lhi]
#pragma unroll
    for (int ni = 0; ni < 4; ++ni) {
        int rloc = w * 64 + ni * 16 + l15;
        int2 p;
        p.x = __float_as_int(tv0[ni]);
        p.y = __float_as_int(tv1[ni]);
        mrg[rloc * 4 + lhi] = p;
    }
    __syncthreads();
    {
        float b0 = NEG_INF_F, b1 = NEG_INF_F, b2 = NEG_INF_F;
#pragma unroll
        for (int q = 0; q < 4; ++q) {
            int2 p = mrg[t * 4 + q];
            int ks[2] = {p.x, p.y};
#pragma unroll
            for (int j = 0; j < 2; ++j) {
                float k = __int_as_float(ks[j]), h;
                h = fmaxf(b0, k); k = fminf(b0, k); b0 = h;
                h = fmaxf(b1, k); k = fminf(b1, k); b1 = h;
                b2 = fmaxf(b2, k);
            }
        }
        int rowG = rowBase + t;
        int* o = cand_row + (size_t)rowG * 24 + split * 3;
        o[0] = colBase + (__float_as_int(b0) & 0xFFF);
        o[1] = colBase + (__float_as_int(b1) & 0xFFF);
        o[2] = colBase + (__float_as_int(b2) & 0xFFF);
    }
}

// ------------------------------------------------------------------
// mergecol: per column, bf16-key top-6 of 192 block partials -> rows
// ------------------------------------------------------------------
__global__ __launch_bounds__(256) void mergecol_kernel(
    const unsigned* __restrict__ cand_col, int* __restrict__ col6)
{
    int col = blockIdx.x * 256 + threadIdx.x;   // 0..16383
    float bv0 = NEG_INF_F, bv1 = NEG_INF_F, bv2 = NEG_INF_F;
    float bv3 = NEG_INF_F, bv4 = NEG_INF_F, bv5 = NEG_INF_F;
    for (int s = 0; s < NCOLSLOT; ++s) {
        float k = __uint_as_float(cand_col[(size_t)s * NP + col]);
        float h;
        h = fmaxf(bv0, k); k = fminf(bv0, k); bv0 = h;
        h = fmaxf(bv1, k); k = fminf(bv1, k); bv1 = h;
        h = fmaxf(bv2, k); k = fminf(bv2, k); bv2 = h;
        h = fmaxf(bv3, k); k = fminf(bv3, k); bv3 = h;
        h = fmaxf(bv4, k); k = fminf(bv4, k); bv4 = h;
        bv5 = fmaxf(bv5, k);
    }
    const float thr = bv5;
    int r0 = 0, r1 = 0, r2 = 0, r3 = 0, r4 = 0, r5 = 0;
    int cnt = 0;
    for (int s = 0; s < NCOLSLOT; ++s) {
        unsigned ku = cand_col[(size_t)s * NP + col];
        float k = __uint_as_float(ku);
        bool take = (k >= thr) && (cnt < 6);
        int row = (s / 3) * 256 + (int)(ku & 0xFFu);
        r0 = (take && cnt == 0) ? row : r0;
        r1 = (take && cnt == 1) ? row : r1;
        r2 = (take && cnt == 2) ? row : r2;
        r3 = (take && cnt == 3) ? row : r3;
        r4 = (take && cnt == 4) ? row : r4;
        r5 = (take && cnt == 5) ? row : r5;
        cnt += take ? 1 : 0;
    }
    int* o = col6 + (size_t)col * 6;
    o[0] = r0; o[1] = r1; o[2] = r2; o[3] = r3; o[4] = r4; o[5] = r5;
}

// ------------------------------------------------------------------
// rescore_row: exact fp32 top-2 over 24 cands per row (wave per row)
// ------------------------------------------------------------------
__global__ __launch_bounds__(256) void rescore_row_kernel(
    const float* __restrict__ AT, const float* __restrict__ BT,
    const int* __restrict__ cand_row, float4* __restrict__ final12)
{
    const int t = threadIdx.x;
    const int w = t >> 6, l = t & 63;
    const int row = blockIdx.x * 4 + w;    // 0..16383
    float4 rv = *(const float4*)(AT + ((size_t)row << 8) + l * 4);
    float v0 = -4.f, v1 = -4.f; int i0 = 0x7fffffff, i1 = 0x7fffffff;
    const int* __restrict__ cl = cand_row + (size_t)row * 24;
#pragma unroll 4
    for (int j = 0; j < 24; ++j) {
        int idx = cl[j];
        float4 cv = *(const float4*)(BT + ((size_t)idx << 8) + l * 4);
        float d = rv.x * cv.x;
        d = fmaf(rv.y, cv.y, d);
        d = fmaf(rv.z, cv.z, d);
        d = fmaf(rv.w, cv.w, d);
#pragma unroll
        for (int m = 1; m < 64; m <<= 1) d += __shfl_xor(d, m, 64);
        if (d > v0 || (d == v0 && idx < i0)) {
            v1 = v0; i1 = i0; v0 = d; i0 = idx;
        } else if (d > v1 || (d == v1 && idx < i1)) {
            v1 = d; i1 = idx;
        }
    }
    if (l == 0) {
        float4 r; r.x = v0; r.y = v1;
        r.z = __int_as_float(i0); r.w = __int_as_float(i1);
        final12[row] = r;
    }
}

// ------------------------------------------------------------------
// rescore_col: exact fp32 top-2 over 6 cands per column (wave per col)
// ------------------------------------------------------------------
__global__ __launch_bounds__(256) void rescore_col_kernel(
    const float* __restrict__ AT, const float* __restrict__ BT,
    const int* __restrict__ col6,
    int* __restrict__ nn21, float* __restrict__ ratio21)
{
    const int t = threadIdx.x;
    const int w = t >> 6, l = t & 63;
    const int col = blockIdx.x * 4 + w;    // 0..16383
    float4 rv = *(const float4*)(BT + ((size_t)col << 8) + l * 4);
    float v0 = -4.f, v1 = -4.f; int i0 = 0x7fffffff, i1 = 0x7fffffff;
    const int* __restrict__ cl = col6 + (size_t)col * 6;
#pragma unroll
    for (int j = 0; j < 6; ++j) {
        int idx = cl[j];
        float4 cv = *(const float4*)(AT + ((size_t)idx << 8) + l * 4);
        float d = rv.x * cv.x;
        d = fmaf(rv.y, cv.y, d);
        d = fmaf(rv.z, cv.z, d);
        d = fmaf(rv.w, cv.w, d);
#pragma unroll
        for (int m = 1; m < 64; m <<= 1) d += __shfl_xor(d, m, 64);
        if (d > v0 || (d == v0 && idx < i0)) {
            v1 = v0; i1 = i0; v0 = d; i0 = idx;
        } else if (d > v1 || (d == v1 && idx < i1)) {
            v1 = d; i1 = idx;
        }
    }
    if (l == 0) {
        nn21[col] = i0;
        float d0 = sqrtf(fmaxf(2.f - 2.f * v0, 1e-12f));
        float d1 = sqrtf(fmaxf(2.f - 2.f * v1, 1e-12f));
        ratio21[col] = d0 / (d1 + EPSF);
    }
}

// ------------------------------------------------------------------
// final: mutual check, ratio test, border mask
// ------------------------------------------------------------------
__global__ void final_kernel(const float4* __restrict__ final12,
                             const int* __restrict__ nn21,
                             const float* __restrict__ ratio21,
                             float* __restrict__ out) {
    int i = blockIdx.x * blockDim.x + threadIdx.x;  // 0..16383
    float4 a = final12[i];
    float d0 = sqrtf(fmaxf(2.f - 2.f * a.x, 1e-12f));
    float d1 = sqrtf(fmaxf(2.f - 2.f * a.y, 1e-12f));
    int nn = __float_as_int(a.z);
    float r12 = d0 / (d1 + EPSF);
    bool mutual = (nn21[nn] == i);
    float r = fmaxf(r12, ratio21[nn]);
    int xA = i & (WDIM - 1), yA = i >> 7;
    int xB = nn & (WDIM - 1), yB = nn >> 7;
    bool border = (xA == 0) || (xA == WDIM - 1) || (yA == 0) || (yA == WDIM - 1) ||
                  (xB == 0) || (xB == WDIM - 1) || (yB == 0) || (yB == WDIM - 1);
    bool valid = mutual && (r < 0.95f) && !border;
    out[2 * i]       = valid ? d0 : 0.f;
    out[2 * i + 1]   = valid ? d1 : 0.f;
    out[2 * NP + i]  = (float)nn;
    out[3 * NP + i]  = valid ? 1.f : 0.f;
}

extern "C" void kernel_launch(void* const* d_in, const int* in_sizes, int n_in,
                              void* d_out, int out_size, void* d_ws, size_t ws_size,
                              hipStream_t stream) {
    (void)in_sizes; (void)n_in; (void)out_size; (void)ws_size;
    const float* A = (const float*)d_in[0];
    const float* B = (const float*)d_in[1];
    float* out = (float*)d_out;

    char* ws = (char*)d_ws;
    float* AT = (float*)ws;                                          // 16 MB
    float* BT = AT + (size_t)NP * CH;                                // 16 MB
    unsigned short* Abf = (unsigned short*)(BT + (size_t)NP * CH);   // 8 MB
    unsigned short* Bbf = Abf + (size_t)NP * CH;                     // 8 MB
    int* cand_row = (int*)(Bbf + (size_t)NP * CH);                   // 1.5 MB
    unsigned* cand_col = (unsigned*)(cand_row + (size_t)NP * 24);    // 12.6 MB
    int* col6 = (int*)(cand_col + (size_t)NCOLSLOT * NP);            // 0.4 MB
    float4* final12 = (float4*)(col6 + (size_t)NP * 6);              // 256 KB
    int* nn21 = (int*)(final12 + NP);                                // 64 KB
    float* ratio21 = (float*)(nn21 + NP);                            // 64 KB

    prep_kernel<<<512, 256, 0, stream>>>(A, B, AT, BT, Abf, Bbf);
    simk_kernel<<<NRT * SPLITS, 256, 0, stream>>>(Abf, Bbf, cand_row, cand_col);
    mergecol_kernel<<<NP / 256, 256, 0, stream>>>(cand_col, col6);
    rescore_row_kernel<<<NP / 4, 256, 0, stream>>>(AT, BT, cand_row, final12);
    rescore_col_kernel<<<NP / 4, 256, 0, stream>>>(AT, BT, col6, nn21, ratio21);
    final_kernel<<<NP / 256, 256, 0, stream>>>(final12, nn21, ratio21, out);
}